// Round 1
// 1275.716 us; speedup vs baseline: 1.1049x; 1.1049x over previous
//
#include <hip/hip_runtime.h>
#include <hip/hip_bf16.h>

#define MTOT 8192              // B*T
#define TLEN 4096              // T
#define CDIM 2048              // C
#define SLOT ((size_t)MTOT * CDIM)   // elements per output tensor

typedef __attribute__((ext_vector_type(4))) float f32x4;
typedef __attribute__((ext_vector_type(8))) __bf16 bf16x8;

__device__ __forceinline__ short f2bf(float f) {
  __hip_bfloat16 h = __float2bfloat16(f);
  return __builtin_bit_cast(short, h);
}

__device__ __forceinline__ float sigm(float x) { return 1.f / (1.f + expf(-x)); }

// async global->LDS, 16B per lane; LDS dest = wave-uniform base + lane*16
__device__ __forceinline__ void gload16(const void* g, void* l) {
  __builtin_amdgcn_global_load_lds(
      (__attribute__((address_space(1))) void*)g,
      (__attribute__((address_space(3))) void*)l, 16, 0, 0);
}

// ---------------------------------------------------------------------------
// Core 128x128 tile GEMM (NT): C[m,n] = sum_k A[m,k] * Bt[n,k]
// block = 256 threads (4 waves), BK=32, 16x16x32 bf16 MFMA, 4x4 acc per wave
// (kept for the small LoRA GEMMs gemm_s1 / gemm_s2)
// ---------------------------------------------------------------------------
__device__ __forceinline__ void gemm_core(
    const short* __restrict__ A, int lda,
    const short* __restrict__ Bt, int ldb,
    int K, int m0, int n0,
    short* As, short* Bs, f32x4 acc[4][4])
{
  const int tid  = threadIdx.x;
  const int lane = tid & 63;
  const int wv   = tid >> 6;        // wave 0..3
  const int wy   = wv >> 1;
  const int wx   = wv & 1;
  const int quad = lane >> 4;
  const int m16  = lane & 15;

  const f32x4 zero = {0.f, 0.f, 0.f, 0.f};
  #pragma unroll
  for (int i = 0; i < 4; ++i)
    #pragma unroll
    for (int j = 0; j < 4; ++j)
      acc[i][j] = zero;

  // staging geometry: tile = 128 rows x 32 cols bf16 (8 KB). Two chunks per wave.
  const int e0 = (wv * 64 + lane) * 8;   // element offset of chunk 0
  const int e1 = e0 + 2048;              // chunk 1
  const int r0 = e0 >> 5, c0 = e0 & 31;
  const int r1 = e1 >> 5, c1 = e1 & 31;
  const int lb0 = wv * 512;              // LDS base (elems), wave-uniform
  const int lb1 = 2048 + wv * 512;

  const short* pa0 = A  + (size_t)(m0 + r0) * lda + c0;
  const short* pa1 = A  + (size_t)(m0 + r1) * lda + c1;
  const short* pb0 = Bt + (size_t)(n0 + r0) * ldb + c0;
  const short* pb1 = Bt + (size_t)(n0 + r1) * ldb + c1;

  for (int k0 = 0; k0 < K; k0 += 32) {
    gload16(pa0 + k0, As + lb0);
    gload16(pa1 + k0, As + lb1);
    gload16(pb0 + k0, Bs + lb0);
    gload16(pb1 + k0, Bs + lb1);
    __syncthreads();

    bf16x8 af[4], bfr[4];
    #pragma unroll
    for (int mi = 0; mi < 4; ++mi)
      af[mi] = *(const bf16x8*)(As + (wy*64 + mi*16 + m16)*32 + quad*8);
    #pragma unroll
    for (int ni = 0; ni < 4; ++ni)
      bfr[ni] = *(const bf16x8*)(Bs + (wx*64 + ni*16 + m16)*32 + quad*8);

    #pragma unroll
    for (int mi = 0; mi < 4; ++mi)
      #pragma unroll
      for (int ni = 0; ni < 4; ++ni)
        acc[mi][ni] = __builtin_amdgcn_mfma_f32_16x16x32_bf16(
            af[mi], bfr[ni], acc[mi][ni], 0, 0, 0);
    __syncthreads();
  }
}

// ---------------------------------------------------------------------------
// Elementwise mix: xx = xprev - x; out_j = bf16(x + xx*coef_j); also v_first copy
// ---------------------------------------------------------------------------
__global__ __launch_bounds__(256) void mix_kernel(
    const float* __restrict__ x, const float* __restrict__ vfin,
    const float* __restrict__ cr, const float* __restrict__ cw,
    const float* __restrict__ ck, const float* __restrict__ cv,
    const float* __restrict__ ca, const float* __restrict__ cg,
    short* __restrict__ xr, short* __restrict__ xw, short* __restrict__ xk,
    short* __restrict__ xv, short* __restrict__ xa, short* __restrict__ xg,
    float* __restrict__ vfout)
{
  const size_t i = (size_t)blockIdx.x * 256 + threadIdx.x;  // over MTOT*CDIM/4
  const size_t e = i * 4;
  const int c = (int)(e & (CDIM - 1));
  const size_t m = e >> 11;            // / CDIM
  const int t = (int)(m & (TLEN - 1));
  const float4 xc = *(const float4*)(x + e);
  float4 xp = make_float4(0.f, 0.f, 0.f, 0.f);
  if (t > 0) xp = *(const float4*)(x + e - CDIM);
  const float d0 = xp.x - xc.x, d1 = xp.y - xc.y;
  const float d2 = xp.z - xc.z, d3 = xp.w - xc.w;

  *(float4*)(vfout + e) = *(const float4*)(vfin + e);

  #define EMIT(coef, dst) { \
    const float4 cf = *(const float4*)((coef) + c); \
    short4 s; \
    s.x = f2bf(xc.x + d0 * cf.x); \
    s.y = f2bf(xc.y + d1 * cf.y); \
    s.z = f2bf(xc.z + d2 * cf.z); \
    s.w = f2bf(xc.w + d3 * cf.w); \
    *(short4*)((dst) + e) = s; }
  EMIT(cr, xr) EMIT(cw, xw) EMIT(ck, xk) EMIT(cv, xv) EMIT(ca, xa) EMIT(cg, xg)
  #undef EMIT
}

// fp32 -> bf16 straight convert for Wr/Wk/Wv
__global__ __launch_bounds__(256) void cvt_big(
    const float* __restrict__ Wr, const float* __restrict__ Wk,
    const float* __restrict__ Wv,
    short* __restrict__ br, short* __restrict__ bk, short* __restrict__ bv)
{
  const int z = blockIdx.y;
  const float* src = (z == 0) ? Wr : (z == 1) ? Wk : Wv;
  short* dst = (z == 0) ? br : (z == 1) ? bk : bv;
  const size_t e = ((size_t)blockIdx.x * 256 + threadIdx.x) * 4;  // over CDIM*CDIM
  const float4 v = *(const float4*)(src + e);
  short4 s;
  s.x = f2bf(v.x); s.y = f2bf(v.y); s.z = f2bf(v.z); s.w = f2bf(v.w);
  *(short4*)(dst + e) = s;
}

// transpose (+zero-pad) small weights into bf16 [N,K] ("B^T") layout
__global__ __launch_bounds__(256) void wtrans(
    const float* __restrict__ w1, const float* __restrict__ a1,
    const float* __restrict__ v1, const float* __restrict__ g1,
    const float* __restrict__ w2, const float* __restrict__ a2,
    const float* __restrict__ v2, const float* __restrict__ g2,
    short* __restrict__ w1t, short* __restrict__ a1t,
    short* __restrict__ v1t, short* __restrict__ g1t,
    short* __restrict__ w2t, short* __restrict__ a2t,
    short* __restrict__ v2t, short* __restrict__ g2t)
{
  const int task = blockIdx.y;
  const int i = blockIdx.x * 256 + threadIdx.x;
  switch (task) {
    case 0: if (i < 128*2048) { int d=i>>11, c=i&2047; w1t[i]=f2bf(w1[(size_t)c*128+d]); } break;
    case 1: if (i < 128*2048) { int d=i>>11, c=i&2047; a1t[i]=f2bf(a1[(size_t)c*128+d]); } break;
    case 2: if (i < 128*2048) { int d=i>>11, c=i&2047; v1t[i]=(d<64)?f2bf(v1[(size_t)c*64+d]):(short)0; } break;
    case 3: if (i < 256*2048) { int d=i>>11, c=i&2047; g1t[i]=(d<224)?f2bf(g1[(size_t)c*224+d]):(short)0; } break;
    case 4: if (i < 2048*128) { int c=i>>7, d=i&127; w2t[i]=f2bf(w2[(size_t)d*2048+c]); } break;
    case 5: if (i < 2048*128) { int c=i>>7, d=i&127; a2t[i]=f2bf(a2[(size_t)d*2048+c]); } break;
    case 6: if (i < 2048*64)  { int c=i>>6, d=i&63;  v2t[i]=f2bf(v2[(size_t)d*2048+c]); } break;
    case 7: if (i < 2048*224) { int c=i/224, d=i-c*224; g2t[i]=f2bf(g2[(size_t)d*2048+c]); } break;
  }
}

// ---------------------------------------------------------------------------
// big projections, 256x256 tile, BK=64, 8 waves, 4-phase/K-tile counted-vmcnt
// pipeline (T2 swizzle + T3/T4 counted vmcnt + T5 setprio).
//   r = xr@Wr^T -> slot0 ; kraw = xk@Wk^T -> slot2 ; vraw = xv@Wv^T -> slot3
//
// LDS layout: As/Bs = [dbuf][kshalf][256 rows][32 cols] bf16, 16KB per half.
// Within a 64B row, 16B slot s holds global col-chunk (s ^ ((row>>1)&3)) --
// the source address is pre-swizzled so global_load_lds can write linearly,
// and ds_read applies the same XOR (bijective involution, rule #21).
// Gates: vmcnt(4) before each half-pair is consumed (4 half-tile loads always
// in flight); drains to 0 only in the last K-tile.
// ---------------------------------------------------------------------------
__global__ __launch_bounds__(512, 2) void gemm_big2(
    const short* __restrict__ xr, const short* __restrict__ xk,
    const short* __restrict__ xv,
    const short* __restrict__ Wr, const short* __restrict__ Wk,
    const short* __restrict__ Wv,
    float* __restrict__ out)
{
  __shared__ short As[32768];   // 64KB: [db:16384][ks:8192] elems
  __shared__ short Bs[32768];   // 64KB

  const int z = blockIdx.z;
  const short* A  = (z == 0) ? xr : (z == 1) ? xk : xv;
  const short* Bt = (z == 0) ? Wr : (z == 1) ? Wk : Wv;
  float* O = (z == 0) ? out : (z == 1) ? out + 2*SLOT : out + 3*SLOT;

  const int m0 = blockIdx.x * 256, n0 = blockIdx.y * 256;
  const int tid  = threadIdx.x;          // 0..511
  const int lane = tid & 63, wid = tid >> 6;
  const int wm = wid >> 2, wn = wid & 3; // 2 x 4 wave grid
  const int quad = lane >> 4, m16 = lane & 15;

  // ---- staging geometry (per thread, constant over K) ----
  const int srow = tid >> 2;                                 // 0..127
  const int csrc = (((tid & 3) ^ ((tid >> 3) & 3)) << 3);    // pre-swizzled col chunk
  const size_t aoff = (size_t)(m0 + srow) * CDIM + csrc;
  const size_t boff = (size_t)(n0 + srow) * CDIM + csrc;
  const int lbase = wid * 512;           // wave-uniform lane0 elem offset (j=0)

  // ---- fragment read offsets (swizzled) ----
  const int fslot = ((quad ^ ((m16 >> 1) & 3)) << 3);        // elem offset in row
  const int abase = (wm*128 + m16) * 32 + fslot;
  const int bbase = (wn*64  + m16) * 32 + fslot;

  f32x4 acc[8][4];
  const f32x4 zf = {0.f, 0.f, 0.f, 0.f};
  #pragma unroll
  for (int i = 0; i < 8; ++i)
    #pragma unroll
    for (int j = 0; j < 4; ++j) acc[i][j] = zf;

  // stage one 256x32 half (2 x global_load_lds per thread)
  #define STG(REG, BASEP, OFF, KOFF) do { \
    gload16((BASEP) + (OFF) + (KOFF), (REG) + lbase); \
    gload16((BASEP) + (OFF) + (KOFF) + (size_t)128*CDIM, (REG) + lbase + 4096); \
  } while (0)

  // prologue: tile 0 into dbuf 0, order A_k0, B_k0, A_k1, B_k1
  STG(As + 0,    A,  aoff, 0);
  STG(Bs + 0,    Bt, boff, 0);
  STG(As + 8192, A,  aoff, 32);
  STG(Bs + 8192, Bt, boff, 32);
  asm volatile("s_waitcnt vmcnt(4)" ::: "memory");   // k0 halves resident
  __builtin_amdgcn_s_barrier();
  __builtin_amdgcn_sched_barrier(0);

  const int NT = CDIM / 64;
  for (int t = 0; t < NT; ++t) {
    const int db = (t & 1) << 14;        // 0 / 16384
    const int nb = 16384 - db;
    const int kn = t*64 + 64;
    const bool pf = (kn < CDIM);
    short* Ar0 = As + db;                // tile t, ks=0
    short* Br0 = Bs + db;
    short* Ar1 = As + db + 8192;         // tile t, ks=1
    short* Br1 = Bs + db + 8192;

    bf16x8 af[8], b0, b1;

    // ---------- P1: ks0, ni 0-1 ----------
    #pragma unroll
    for (int mi = 0; mi < 8; ++mi)
      af[mi] = *(const bf16x8*)(Ar0 + abase + mi*512);
    b0 = *(const bf16x8*)(Br0 + bbase + 0*512);
    b1 = *(const bf16x8*)(Br0 + bbase + 1*512);
    if (pf) STG(As + nb, A, aoff, kn);
    __builtin_amdgcn_s_barrier();
    asm volatile("s_waitcnt lgkmcnt(0)" ::: "memory");
    __builtin_amdgcn_sched_barrier(0);
    __builtin_amdgcn_s_setprio(1);
    #pragma unroll
    for (int mi = 0; mi < 8; ++mi)
      acc[mi][0] = __builtin_amdgcn_mfma_f32_16x16x32_bf16(af[mi], b0, acc[mi][0], 0, 0, 0);
    #pragma unroll
    for (int mi = 0; mi < 8; ++mi)
      acc[mi][1] = __builtin_amdgcn_mfma_f32_16x16x32_bf16(af[mi], b1, acc[mi][1], 0, 0, 0);
    __builtin_amdgcn_s_setprio(0);
    __builtin_amdgcn_s_barrier();

    // ---------- P2: ks0, ni 2-3 ----------
    b0 = *(const bf16x8*)(Br0 + bbase + 2*512);
    b1 = *(const bf16x8*)(Br0 + bbase + 3*512);
    if (pf) STG(Bs + nb, Bt, boff, kn);
    __builtin_amdgcn_s_barrier();
    asm volatile("s_waitcnt lgkmcnt(0)" ::: "memory");
    __builtin_amdgcn_sched_barrier(0);
    __builtin_amdgcn_s_setprio(1);
    #pragma unroll
    for (int mi = 0; mi < 8; ++mi)
      acc[mi][2] = __builtin_amdgcn_mfma_f32_16x16x32_bf16(af[mi], b0, acc[mi][2], 0, 0, 0);
    #pragma unroll
    for (int mi = 0; mi < 8; ++mi)
      acc[mi][3] = __builtin_amdgcn_mfma_f32_16x16x32_bf16(af[mi], b1, acc[mi][3], 0, 0, 0);
    __builtin_amdgcn_s_setprio(0);
    if (pf) asm volatile("s_waitcnt vmcnt(4)" ::: "memory");  // k1 halves of tile t
    else    asm volatile("s_waitcnt vmcnt(0)" ::: "memory");
    __builtin_amdgcn_s_barrier();
    __builtin_amdgcn_sched_barrier(0);

    // ---------- P3: ks1, ni 0-1 ----------
    #pragma unroll
    for (int mi = 0; mi < 8; ++mi)
      af[mi] = *(const bf16x8*)(Ar1 + abase + mi*512);
    b0 = *(const bf16x8*)(Br1 + bbase + 0*512);
    b1 = *(const bf16x8*)(Br1 + bbase + 1*512);
    if (pf) STG(As + nb + 8192, A, aoff, kn + 32);
    __builtin_amdgcn_s_barrier();
    asm volatile("s_waitcnt lgkmcnt(0)" ::: "memory");
    __builtin_amdgcn_sched_barrier(0);
    __builtin_amdgcn_s_setprio(1);
    #pragma unroll
    for (int mi = 0; mi < 8; ++mi)
      acc[mi][0] = __builtin_amdgcn_mfma_f32_16x16x32_bf16(af[mi], b0, acc[mi][0], 0, 0, 0);
    #pragma unroll
    for (int mi = 0; mi < 8; ++mi)
      acc[mi][1] = __builtin_amdgcn_mfma_f32_16x16x32_bf16(af[mi], b1, acc[mi][1], 0, 0, 0);
    __builtin_amdgcn_s_setprio(0);
    __builtin_amdgcn_s_barrier();

    // ---------- P4: ks1, ni 2-3 ----------
    b0 = *(const bf16x8*)(Br1 + bbase + 2*512);
    b1 = *(const bf16x8*)(Br1 + bbase + 3*512);
    if (pf) STG(Bs + nb + 8192, Bt, boff, kn + 32);
    __builtin_amdgcn_s_barrier();
    asm volatile("s_waitcnt lgkmcnt(0)" ::: "memory");
    __builtin_amdgcn_sched_barrier(0);
    __builtin_amdgcn_s_setprio(1);
    #pragma unroll
    for (int mi = 0; mi < 8; ++mi)
      acc[mi][2] = __builtin_amdgcn_mfma_f32_16x16x32_bf16(af[mi], b0, acc[mi][2], 0, 0, 0);
    #pragma unroll
    for (int mi = 0; mi < 8; ++mi)
      acc[mi][3] = __builtin_amdgcn_mfma_f32_16x16x32_bf16(af[mi], b1, acc[mi][3], 0, 0, 0);
    __builtin_amdgcn_s_setprio(0);
    asm volatile("s_waitcnt vmcnt(4)" ::: "memory");  // k0 halves of tile t+1
    __builtin_amdgcn_s_barrier();
    __builtin_amdgcn_sched_barrier(0);
  }
  #undef STG

  // epilogue: same C/D mapping as the verified 128^2 kernel
  #pragma unroll
  for (int mi = 0; mi < 8; ++mi) {
    const int row = m0 + wm*128 + mi*16 + quad*4;
    #pragma unroll
    for (int ni = 0; ni < 4; ++ni) {
      const int col = n0 + wn*64 + ni*16 + m16;
      #pragma unroll
      for (int r = 0; r < 4; ++r)
        O[(size_t)(row + r) * CDIM + col] = acc[mi][ni][r];
    }
  }
}

// stage-1 LoRA: h_w=tanh(xw@w1), h_a=xa@a1, h_v=xv@v1, h_g=sigmoid(xg@g1)  (bf16 out)
__global__ __launch_bounds__(256) void gemm_s1(
    const short* __restrict__ xw, const short* __restrict__ xa,
    const short* __restrict__ xv, const short* __restrict__ xg,
    const short* __restrict__ w1t, const short* __restrict__ a1t,
    const short* __restrict__ v1t, const short* __restrict__ g1t,
    short* __restrict__ hw, short* __restrict__ ha,
    short* __restrict__ hv, short* __restrict__ hg)
{
  const int z = blockIdx.z;
  const int nb = blockIdx.y;
  if (z != 3 && nb != 0) return;      // only g has 2 n-blocks
  __shared__ short As[4096], Bs[4096];
  const short* A  = (z==0) ? xw  : (z==1) ? xa  : (z==2) ? xv  : xg;
  const short* Bt = (z==0) ? w1t : (z==1) ? a1t : (z==2) ? v1t : g1t;
  short* H        = (z==0) ? hw  : (z==1) ? ha  : (z==2) ? hv  : hg;
  const int Nreal = (z==2) ? 64 : (z==3) ? 224 : 128;
  const int m0 = blockIdx.x * 128, n0 = nb * 128;
  f32x4 acc[4][4];
  gemm_core(A, CDIM, Bt, CDIM, CDIM, m0, n0, As, Bs, acc);

  const int tid=threadIdx.x, lane=tid&63, wv=tid>>6;
  const int wy=wv>>1, wx=wv&1, quad=lane>>4, m16=lane&15;
  #pragma unroll
  for (int mi = 0; mi < 4; ++mi) {
    const int mb = m0 + wy*64 + mi*16 + quad*4;
    #pragma unroll
    for (int ni = 0; ni < 4; ++ni) {
      const int n = n0 + wx*64 + ni*16 + m16;
      if (n < Nreal) {
        #pragma unroll
        for (int r = 0; r < 4; ++r) {
          float v = acc[mi][ni][r];
          if (z == 0) v = tanhf(v);
          else if (z == 3) v = sigm(v);
          H[(size_t)(mb + r) * Nreal + n] = f2bf(v);
        }
      }
    }
  }
}

// stage-2 LoRA with fused epilogues:
//  z0: w = -softplus(-(w0 + hw@w2)) - 0.5        -> slot1
//  z1: a = sigmoid(a0 + ha@a2)                   -> slot4
//  z2: v = vraw + (v_first - vraw)*sigmoid(v0 + hv@v2)   (in-place slot3)
//  z3: g = hg@g2                                 -> slot5
__global__ __launch_bounds__(256) void gemm_s2(
    const short* __restrict__ hw, const short* __restrict__ ha,
    const short* __restrict__ hv, const short* __restrict__ hg,
    const short* __restrict__ w2t, const short* __restrict__ a2t,
    const short* __restrict__ v2t, const short* __restrict__ g2t,
    const float* __restrict__ w0, const float* __restrict__ a0,
    const float* __restrict__ v0, const float* __restrict__ vfirst,
    float* __restrict__ out)
{
  __shared__ short As[4096], Bs[4096];
  const int z = blockIdx.z;
  const short* A  = (z==0) ? hw  : (z==1) ? ha  : (z==2) ? hv  : hg;
  const short* Bt = (z==0) ? w2t : (z==1) ? a2t : (z==2) ? v2t : g2t;
  const int K = (z==2) ? 64 : (z==3) ? 224 : 128;
  const int m0 = blockIdx.x * 128, n0 = blockIdx.y * 128;
  f32x4 acc[4][4];
  gemm_core(A, K, Bt, K, K, m0, n0, As, Bs, acc);

  const int tid=threadIdx.x, lane=tid&63, wv=tid>>6;
  const int wy=wv>>1, wx=wv&1, quad=lane>>4, m16=lane&15;
  #pragma unroll
  for (int mi = 0; mi < 4; ++mi) {
    const int mb = m0 + wy*64 + mi*16 + quad*4;
    #pragma unroll
    for (int ni = 0; ni < 4; ++ni) {
      const int n = n0 + wx*64 + ni*16 + m16;
      #pragma unroll
      for (int r = 0; r < 4; ++r) {
        const float val = acc[mi][ni][r];
        const size_t idx = (size_t)(mb + r) * CDIM + n;
        if (z == 0) {
          float zz = w0[n] + val;
          float sp = fmaxf(-zz, 0.f) + log1pf(expf(-fabsf(zz)));
          out[SLOT + idx] = -sp - 0.5f;
        } else if (z == 1) {
          out[4*SLOT + idx] = sigm(a0[n] + val);
        } else if (z == 2) {
          const float gate = sigm(v0[n] + val);
          const float vr = out[3*SLOT + idx];
          out[3*SLOT + idx] = vr + (vfirst[idx] - vr) * gate;
        } else {
          out[5*SLOT + idx] = val;
        }
      }
    }
  }
}

// finalize: kk = normalize_per_head(kraw*k_k); k = kraw*(1+(a-1)*k_a)
__global__ __launch_bounds__(256) void fin_k(
    const float* __restrict__ kkc, const float* __restrict__ kac,
    float* __restrict__ out)
{
  const int wid  = blockIdx.x * 4 + (threadIdx.x >> 6);  // row-head id, 0..262143
  const int lane = threadIdx.x & 63;
  const size_t m = (size_t)(wid >> 5);   // / 32 heads
  const int h = wid & 31;
  const int c = h * 64 + lane;
  const size_t idx = m * CDIM + c;
  const float kraw = out[2*SLOT + idx];
  const float a    = out[4*SLOT + idx];
  const float kkv  = kraw * kkc[c];
  float ss = kkv * kkv;
  #pragma unroll
  for (int o = 32; o >= 1; o >>= 1) ss += __shfl_xor(ss, o, 64);
  const float nrm = sqrtf(ss);
  out[6*SLOT + idx] = kkv / fmaxf(nrm, 1e-12f);
  out[2*SLOT + idx] = kraw * (1.f + (a - 1.f) * kac[c]);
}

extern "C" void kernel_launch(void* const* d_in, const int* in_sizes, int n_in,
                              void* d_out, int out_size, void* d_ws, size_t ws_size,
                              hipStream_t stream) {
  (void)in_sizes; (void)n_in; (void)out_size; (void)ws_size;
  const float* x   = (const float*)d_in[0];
  const float* vf  = (const float*)d_in[1];
  const float* x_r = (const float*)d_in[2];
  const float* x_w = (const float*)d_in[3];
  const float* x_k = (const float*)d_in[4];
  const float* x_v = (const float*)d_in[5];
  const float* x_a = (const float*)d_in[6];
  const float* x_g = (const float*)d_in[7];
  const float* w0  = (const float*)d_in[8];
  const float* w1  = (const float*)d_in[9];
  const float* w2  = (const float*)d_in[10];
  const float* a0  = (const float*)d_in[11];
  const float* a1  = (const float*)d_in[12];
  const float* a2  = (const float*)d_in[13];
  const float* v0  = (const float*)d_in[14];
  const float* v1  = (const float*)d_in[15];
  const float* v2  = (const float*)d_in[16];
  const float* g1  = (const float*)d_in[17];
  const float* g2  = (const float*)d_in[18];
  const float* k_k = (const float*)d_in[19];
  const float* k_a = (const float*)d_in[20];
  const float* Wr  = (const float*)d_in[21];
  const float* Wk  = (const float*)d_in[22];
  const float* Wv  = (const float*)d_in[23];

  float* out = (float*)d_out;

  // bf16 mixed activations live in not-yet-final output slots (w,a,g):
  // each slot is 64MB fp32; each bf16 array is 32MB. Dead before those slots
  // are written by gemm_s2 (stream-ordered after gemm_big2 / gemm_s1).
  short* xr_b = (short*)(out + 1*SLOT);
  short* xw_b = xr_b + SLOT;
  short* xk_b = (short*)(out + 4*SLOT);
  short* xv_b = xk_b + SLOT;
  short* xa_b = (short*)(out + 5*SLOT);
  short* xg_b = xa_b + SLOT;

  // workspace: bf16 weights + LoRA hiddens (~40 MB)
  char* wsp = (char*)d_ws;
  size_t off = 0;
  #define ALLOC(var, bytes) short* var = (short*)(wsp + off); off += (((size_t)(bytes)) + 255) & ~(size_t)255;
  ALLOC(Wr_b, (size_t)CDIM*CDIM*2)
  ALLOC(Wk_b, (size_t)CDIM*CDIM*2)
  ALLOC(Wv_b, (size_t)CDIM*CDIM*2)
  ALLOC(w1t, 128*2048*2)
  ALLOC(a1t, 128*2048*2)
  ALLOC(v1t, 128*2048*2)   // zero-padded rows 64..127
  ALLOC(g1t, 256*2048*2)   // zero-padded rows 224..255
  ALLOC(w2t, 2048*128*2)
  ALLOC(a2t, 2048*128*2)
  ALLOC(v2t, 2048*64*2)
  ALLOC(g2t, 2048*224*2)
  ALLOC(hw, (size_t)MTOT*128*2)
  ALLOC(ha, (size_t)MTOT*128*2)
  ALLOC(hv, (size_t)MTOT*64*2)
  ALLOC(hg, (size_t)MTOT*224*2)
  #undef ALLOC

  mix_kernel<<<dim3(16384), 256, 0, stream>>>(
      x, vf, x_r, x_w, x_k, x_v, x_a, x_g,
      xr_b, xw_b, xk_b, xv_b, xa_b, xg_b, out + 7*SLOT);

  cvt_big<<<dim3(4096, 3), 256, 0, stream>>>(Wr, Wk, Wv, Wr_b, Wk_b, Wv_b);

  wtrans<<<dim3(2048, 8), 256, 0, stream>>>(
      w1, a1, v1, g1, w2, a2, v2, g2,
      w1t, a1t, v1t, g1t, w2t, a2t, v2t, g2t);

  gemm_big2<<<dim3(32, 8, 3), 512, 0, stream>>>(
      xr_b, xk_b, xv_b, Wr_b, Wk_b, Wv_b, out);

  gemm_s1<<<dim3(64, 2, 4), 256, 0, stream>>>(
      xw_b, xa_b, xv_b, xg_b, w1t, a1t, v1t, g1t, hw, ha, hv, hg);

  gemm_s2<<<dim3(64, 16, 4), 256, 0, stream>>>(
      hw, ha, hv, hg, w2t, a2t, v2t, g2t, w0, a0, v0, vf, out);

  fin_k<<<dim3(65536), 256, 0, stream>>>(k_k, k_a, out);
}

// Round 3
// 1245.557 us; speedup vs baseline: 1.1317x; 1.0242x over previous
//
#include <hip/hip_runtime.h>
#include <hip/hip_bf16.h>

#define MTOT 8192              // B*T
#define TLEN 4096              // T
#define CDIM 2048              // C
#define SLOT ((size_t)MTOT * CDIM)   // elements per output tensor

typedef __attribute__((ext_vector_type(4))) float f32x4;
typedef __attribute__((ext_vector_type(8))) __bf16 bf16x8;

__device__ __forceinline__ short f2bf(float f) {
  __hip_bfloat16 h = __float2bfloat16(f);
  return __builtin_bit_cast(short, h);
}

__device__ __forceinline__ float sigm(float x) { return 1.f / (1.f + expf(-x)); }

// async global->LDS, 16B per lane; LDS dest = wave-uniform base + lane*16
__device__ __forceinline__ void gload16(const void* g, void* l) {
  __builtin_amdgcn_global_load_lds(
      (__attribute__((address_space(1))) void*)g,
      (__attribute__((address_space(3))) void*)l, 16, 0, 0);
}

// ---------------------------------------------------------------------------
// Core 128x128 tile GEMM (NT): C[m,n] = sum_k A[m,k] * Bt[n,k]
// 256 threads (4 waves), BK=32, 16x16x32 bf16 MFMA, 4x4 acc per wave.
// tid is the LOCAL 0..255 thread id (callers may be 512-thread blocks split
// into two independent halves -- both halves run identical trip counts so
// the __syncthreads() stay block-aligned).
// ---------------------------------------------------------------------------
__device__ __forceinline__ void gemm_core(
    int tid,
    const short* __restrict__ A, int lda,
    const short* __restrict__ Bt, int ldb,
    int K, int m0, int n0,
    short* As, short* Bs, f32x4 acc[4][4])
{
  const int lane = tid & 63;
  const int wv   = tid >> 6;        // wave 0..3 (within half)
  const int wy   = wv >> 1;
  const int wx   = wv & 1;
  const int quad = lane >> 4;
  const int m16  = lane & 15;

  const f32x4 zero = {0.f, 0.f, 0.f, 0.f};
  #pragma unroll
  for (int i = 0; i < 4; ++i)
    #pragma unroll
    for (int j = 0; j < 4; ++j)
      acc[i][j] = zero;

  const int e0 = (wv * 64 + lane) * 8;   // element offset of chunk 0
  const int e1 = e0 + 2048;              // chunk 1
  const int r0 = e0 >> 5, c0 = e0 & 31;
  const int r1 = e1 >> 5, c1 = e1 & 31;
  const int lb0 = wv * 512;              // LDS base (elems), wave-uniform
  const int lb1 = 2048 + wv * 512;

  const short* pa0 = A  + (size_t)(m0 + r0) * lda + c0;
  const short* pa1 = A  + (size_t)(m0 + r1) * lda + c1;
  const short* pb0 = Bt + (size_t)(n0 + r0) * ldb + c0;
  const short* pb1 = Bt + (size_t)(n0 + r1) * ldb + c1;

  for (int k0 = 0; k0 < K; k0 += 32) {
    gload16(pa0 + k0, As + lb0);
    gload16(pa1 + k0, As + lb1);
    gload16(pb0 + k0, Bs + lb0);
    gload16(pb1 + k0, Bs + lb1);
    __syncthreads();

    bf16x8 af[4], bfr[4];
    #pragma unroll
    for (int mi = 0; mi < 4; ++mi)
      af[mi] = *(const bf16x8*)(As + (wy*64 + mi*16 + m16)*32 + quad*8);
    #pragma unroll
    for (int ni = 0; ni < 4; ++ni)
      bfr[ni] = *(const bf16x8*)(Bs + (wx*64 + ni*16 + m16)*32 + quad*8);

    #pragma unroll
    for (int mi = 0; mi < 4; ++mi)
      #pragma unroll
      for (int ni = 0; ni < 4; ++ni)
        acc[mi][ni] = __builtin_amdgcn_mfma_f32_16x16x32_bf16(
            af[mi], bfr[ni], acc[mi][ni], 0, 0, 0);
    __syncthreads();
  }
}

// ---------------------------------------------------------------------------
// front: merged {mix, cvt_big, wtrans} -- independent prep work, one launch.
//  blocks [0,16384)          : mix (xx-coef blends -> bf16, v_first copy)
//  blocks [16384,28672)      : Wr/Wk/Wv fp32->bf16
//  blocks [28672,45056)      : small-weight transpose/pad -> bf16 [N,K]
// ---------------------------------------------------------------------------
__global__ __launch_bounds__(256) void front(
    const float* __restrict__ x, const float* __restrict__ vfin,
    const float* __restrict__ cr, const float* __restrict__ cw,
    const float* __restrict__ ck, const float* __restrict__ cv,
    const float* __restrict__ ca, const float* __restrict__ cg,
    const float* __restrict__ Wr, const float* __restrict__ Wk,
    const float* __restrict__ Wv,
    const float* __restrict__ w1, const float* __restrict__ a1,
    const float* __restrict__ v1, const float* __restrict__ g1,
    const float* __restrict__ w2, const float* __restrict__ a2,
    const float* __restrict__ v2, const float* __restrict__ g2,
    short* __restrict__ xr, short* __restrict__ xw, short* __restrict__ xk,
    short* __restrict__ xv, short* __restrict__ xa, short* __restrict__ xg,
    float* __restrict__ vfout,
    short* __restrict__ Wrb, short* __restrict__ Wkb, short* __restrict__ Wvb,
    short* __restrict__ w1t, short* __restrict__ a1t,
    short* __restrict__ v1t, short* __restrict__ g1t,
    short* __restrict__ w2t, short* __restrict__ a2t,
    short* __restrict__ v2t, short* __restrict__ g2t)
{
  const int b = blockIdx.x;
  const int tidx = threadIdx.x;

  if (b < 16384) {
    // ---- mix ----
    const size_t i = (size_t)b * 256 + tidx;     // over MTOT*CDIM/4
    const size_t e = i * 4;
    const int c = (int)(e & (CDIM - 1));
    const size_t m = e >> 11;                    // / CDIM
    const int t = (int)(m & (TLEN - 1));
    const float4 xc = *(const float4*)(x + e);
    float4 xp = make_float4(0.f, 0.f, 0.f, 0.f);
    if (t > 0) xp = *(const float4*)(x + e - CDIM);
    const float d0 = xp.x - xc.x, d1 = xp.y - xc.y;
    const float d2 = xp.z - xc.z, d3 = xp.w - xc.w;

    *(float4*)(vfout + e) = *(const float4*)(vfin + e);

    #define EMIT(coef, dst) { \
      const float4 cf = *(const float4*)((coef) + c); \
      short4 s; \
      s.x = f2bf(xc.x + d0 * cf.x); \
      s.y = f2bf(xc.y + d1 * cf.y); \
      s.z = f2bf(xc.z + d2 * cf.z); \
      s.w = f2bf(xc.w + d3 * cf.w); \
      *(short4*)((dst) + e) = s; }
    EMIT(cr, xr) EMIT(cw, xw) EMIT(ck, xk) EMIT(cv, xv) EMIT(ca, xa) EMIT(cg, xg)
    #undef EMIT
  } else if (b < 28672) {
    // ---- cvt_big ----
    const int lb = b - 16384;
    const int z = lb >> 12;                      // 0..2
    const int xb = lb & 4095;
    const float* src = (z == 0) ? Wr : (z == 1) ? Wk : Wv;
    short* dst = (z == 0) ? Wrb : (z == 1) ? Wkb : Wvb;
    const size_t e = ((size_t)xb * 256 + tidx) * 4;   // over CDIM*CDIM
    const float4 v = *(const float4*)(src + e);
    short4 s;
    s.x = f2bf(v.x); s.y = f2bf(v.y); s.z = f2bf(v.z); s.w = f2bf(v.w);
    *(short4*)(dst + e) = s;
  } else {
    // ---- wtrans ----
    const int lb = b - 28672;
    const int task = lb >> 11;                   // 0..7
    const int i = (lb & 2047) * 256 + tidx;
    switch (task) {
      case 0: if (i < 128*2048) { int d=i>>11, c=i&2047; w1t[i]=f2bf(w1[(size_t)c*128+d]); } break;
      case 1: if (i < 128*2048) { int d=i>>11, c=i&2047; a1t[i]=f2bf(a1[(size_t)c*128+d]); } break;
      case 2: if (i < 128*2048) { int d=i>>11, c=i&2047; v1t[i]=(d<64)?f2bf(v1[(size_t)c*64+d]):(short)0; } break;
      case 3: if (i < 256*2048) { int d=i>>11, c=i&2047; g1t[i]=(d<224)?f2bf(g1[(size_t)c*224+d]):(short)0; } break;
      case 4: if (i < 2048*128) { int c=i>>7, d=i&127; w2t[i]=f2bf(w2[(size_t)d*2048+c]); } break;
      case 5: if (i < 2048*128) { int c=i>>7, d=i&127; a2t[i]=f2bf(a2[(size_t)d*2048+c]); } break;
      case 6: if (i < 2048*64)  { int c=i>>6, d=i&63;  v2t[i]=f2bf(v2[(size_t)d*2048+c]); } break;
      case 7: if (i < 2048*224) { int c=i/224, d=i-c*224; g2t[i]=f2bf(g2[(size_t)d*2048+c]); } break;
    }
  }
}

// ---------------------------------------------------------------------------
// big projections, 256x256 tile, BK=64, 8 waves, 4-phase/K-tile counted-vmcnt
// pipeline (T2 swizzle + T3/T4 counted vmcnt + T5 setprio).
//   z0: r = xr@Wr^T -> slot0 ; z1: kraw = xk@Wk^T -> slot2 ;
//   z2: vraw = xv@Wv^T -> slot3
//   z3: stage-1 LoRA tiles (two independent 128^2 gemm_core halves per block)
//       -- independent of z0..2, launched in the same dispatch to fill the
//          drain tail instead of serializing as a separate kernel.
//
// XCD-aware decomposition: f = x + 32y; n0 = (f&7)*256, m0 = (f>>3)*256 --
// each XCD keeps ONE 1MB B-panel L2-resident while A streams via L3.
// Counted vmcnt(4): 4 half-tile loads always in flight; drain-0 only at end.
// ---------------------------------------------------------------------------
__global__ __launch_bounds__(512, 2) void gemm_big2(
    const short* __restrict__ xr, const short* __restrict__ xk,
    const short* __restrict__ xv,
    const short* __restrict__ Wr, const short* __restrict__ Wk,
    const short* __restrict__ Wv,
    const short* __restrict__ xw, const short* __restrict__ xa,
    const short* __restrict__ xg,
    const short* __restrict__ w1t, const short* __restrict__ a1t,
    const short* __restrict__ v1t, const short* __restrict__ g1t,
    short* __restrict__ hw, short* __restrict__ ha,
    short* __restrict__ hv, short* __restrict__ hg,
    float* __restrict__ out)
{
  __shared__ short As[32768];   // 64KB: [db:16384][ks:8192] elems
  __shared__ short Bs[32768];   // 64KB

  const int z = blockIdx.z;

  if (z == 3) {
    // ------- stage-1 LoRA path: 160 blocks, 2 independent halves each -------
    const int flat = blockIdx.x + (blockIdx.y << 5);
    if (flat >= 160) return;
    const int sub = threadIdx.x >> 8;            // half 0/1
    const int tid = threadIdx.x & 255;
    const int tile = flat * 2 + sub;             // 0..319
    const int t = tile >> 6;                     // 0..4 task
    const int mt = tile & 63;
    const short* A1 = (t==0) ? xw  : (t==1) ? xa  : (t==2) ? xv  : xg;
    const short* B1 = (t==0) ? w1t : (t==1) ? a1t : (t==2) ? v1t : g1t;
    short* H        = (t==0) ? hw  : (t==1) ? ha  : (t==2) ? hv  : hg;
    const int Nreal = (t==2) ? 64 : (t>=3) ? 224 : 128;
    const int n0 = (t==4) ? 128 : 0;
    const int m0 = mt * 128;
    short* sA = As + sub * 8192;                 // 8KB + 8KB per half
    short* sB = sA + 4096;
    f32x4 acc[4][4];
    gemm_core(tid, A1, CDIM, B1, CDIM, CDIM, m0, n0, sA, sB, acc);

    const int lane=tid&63, wv=tid>>6;
    const int wy=wv>>1, wx=wv&1, quad=lane>>4, m16=lane&15;
    #pragma unroll
    for (int mi = 0; mi < 4; ++mi) {
      const int mb = m0 + wy*64 + mi*16 + quad*4;
      #pragma unroll
      for (int ni = 0; ni < 4; ++ni) {
        const int n = n0 + wx*64 + ni*16 + m16;
        if (n < Nreal) {
          #pragma unroll
          for (int r = 0; r < 4; ++r) {
            float v = acc[mi][ni][r];
            if (t == 0) v = tanhf(v);
            else if (t >= 3) v = sigm(v);
            H[(size_t)(mb + r) * Nreal + n] = f2bf(v);
          }
        }
      }
    }
    return;
  }

  // ---------------- main 256x256 pipelined path ----------------
  const short* A  = (z == 0) ? xr : (z == 1) ? xk : xv;
  const short* Bt = (z == 0) ? Wr : (z == 1) ? Wk : Wv;
  float* O = (z == 0) ? out : (z == 1) ? out + 2*SLOT : out + 3*SLOT;

  const int flat = blockIdx.x + (blockIdx.y << 5);   // 0..255
  const int m0 = (flat >> 3) * 256;                  // 32 m-tiles
  const int n0 = (flat & 7)  * 256;                  // 8 n-tiles == 8 XCDs
  const int tid  = threadIdx.x;          // 0..511
  const int lane = tid & 63, wid = tid >> 6;
  const int wm = wid >> 2, wn = wid & 3; // 2 x 4 wave grid
  const int quad = lane >> 4, m16 = lane & 15;

  // ---- staging geometry (per thread, constant over K) ----
  const int srow = tid >> 2;                                 // 0..127
  const int csrc = (((tid & 3) ^ ((tid >> 3) & 3)) << 3);    // pre-swizzled col chunk
  const size_t aoff = (size_t)(m0 + srow) * CDIM + csrc;
  const size_t boff = (size_t)(n0 + srow) * CDIM + csrc;
  const int lbase = wid * 512;           // wave-uniform lane0 elem offset

  // ---- fragment read offsets (swizzled) ----
  const int fslot = ((quad ^ ((m16 >> 1) & 3)) << 3);        // elem offset in row
  const int abase = (wm*128 + m16) * 32 + fslot;
  const int bbase = (wn*64  + m16) * 32 + fslot;

  f32x4 acc[8][4];
  const f32x4 zf = {0.f, 0.f, 0.f, 0.f};
  #pragma unroll
  for (int i = 0; i < 8; ++i)
    #pragma unroll
    for (int j = 0; j < 4; ++j) acc[i][j] = zf;

  // stage one 256x32 half (2 x global_load_lds per thread)
  #define STG(REG, BASEP, OFF, KOFF) do { \
    gload16((BASEP) + (OFF) + (KOFF), (REG) + lbase); \
    gload16((BASEP) + (OFF) + (KOFF) + (size_t)128*CDIM, (REG) + lbase + 4096); \
  } while (0)

  // prologue: tile 0 into dbuf 0, order A_k0, B_k0, A_k1, B_k1
  STG(As + 0,    A,  aoff, 0);
  STG(Bs + 0,    Bt, boff, 0);
  STG(As + 8192, A,  aoff, 32);
  STG(Bs + 8192, Bt, boff, 32);
  asm volatile("s_waitcnt vmcnt(4)" ::: "memory");   // k0 halves resident
  __builtin_amdgcn_s_barrier();
  __builtin_amdgcn_sched_barrier(0);

  const int NT = CDIM / 64;
  for (int t = 0; t < NT; ++t) {
    const int db = (t & 1) << 14;        // 0 / 16384
    const int nb = 16384 - db;
    const int kn = t*64 + 64;
    const bool pf = (kn < CDIM);
    short* Ar0 = As + db;                // tile t, ks=0
    short* Br0 = Bs + db;
    short* Ar1 = As + db + 8192;         // tile t, ks=1
    short* Br1 = Bs + db + 8192;

    bf16x8 af[8], b0, b1, b2, b3;

    // ---------- P1: ks0 reads (12x ds_read_b128), MFMA ni 0-1 ----------
    #pragma unroll
    for (int mi = 0; mi < 8; ++mi)
      af[mi] = *(const bf16x8*)(Ar0 + abase + mi*512);
    b0 = *(const bf16x8*)(Br0 + bbase + 0*512);
    b1 = *(const bf16x8*)(Br0 + bbase + 1*512);
    b2 = *(const bf16x8*)(Br0 + bbase + 2*512);
    b3 = *(const bf16x8*)(Br0 + bbase + 3*512);
    if (pf) STG(As + nb, A, aoff, kn);
    __builtin_amdgcn_s_barrier();
    asm volatile("s_waitcnt lgkmcnt(0)" ::: "memory");
    __builtin_amdgcn_sched_barrier(0);
    __builtin_amdgcn_s_setprio(1);
    #pragma unroll
    for (int mi = 0; mi < 8; ++mi)
      acc[mi][0] = __builtin_amdgcn_mfma_f32_16x16x32_bf16(af[mi], b0, acc[mi][0], 0, 0, 0);
    #pragma unroll
    for (int mi = 0; mi < 8; ++mi)
      acc[mi][1] = __builtin_amdgcn_mfma_f32_16x16x32_bf16(af[mi], b1, acc[mi][1], 0, 0, 0);
    __builtin_amdgcn_s_setprio(0);
    __builtin_amdgcn_s_barrier();

    // ---------- P2: no ds_reads, MFMA ni 2-3 ----------
    if (pf) STG(Bs + nb, Bt, boff, kn);
    __builtin_amdgcn_s_barrier();
    __builtin_amdgcn_s_setprio(1);
    #pragma unroll
    for (int mi = 0; mi < 8; ++mi)
      acc[mi][2] = __builtin_amdgcn_mfma_f32_16x16x32_bf16(af[mi], b2, acc[mi][2], 0, 0, 0);
    #pragma unroll
    for (int mi = 0; mi < 8; ++mi)
      acc[mi][3] = __builtin_amdgcn_mfma_f32_16x16x32_bf16(af[mi], b3, acc[mi][3], 0, 0, 0);
    __builtin_amdgcn_s_setprio(0);
    if (pf) asm volatile("s_waitcnt vmcnt(4)" ::: "memory");  // k1 halves of tile t
    else    asm volatile("s_waitcnt vmcnt(0)" ::: "memory");
    __builtin_amdgcn_s_barrier();
    __builtin_amdgcn_sched_barrier(0);

    // ---------- P3: ks1 reads (12x), MFMA ni 0-1 ----------
    #pragma unroll
    for (int mi = 0; mi < 8; ++mi)
      af[mi] = *(const bf16x8*)(Ar1 + abase + mi*512);
    b0 = *(const bf16x8*)(Br1 + bbase + 0*512);
    b1 = *(const bf16x8*)(Br1 + bbase + 1*512);
    b2 = *(const bf16x8*)(Br1 + bbase + 2*512);
    b3 = *(const bf16x8*)(Br1 + bbase + 3*512);
    if (pf) STG(As + nb + 8192, A, aoff, kn + 32);
    __builtin_amdgcn_s_barrier();
    asm volatile("s_waitcnt lgkmcnt(0)" ::: "memory");
    __builtin_amdgcn_sched_barrier(0);
    __builtin_amdgcn_s_setprio(1);
    #pragma unroll
    for (int mi = 0; mi < 8; ++mi)
      acc[mi][0] = __builtin_amdgcn_mfma_f32_16x16x32_bf16(af[mi], b0, acc[mi][0], 0, 0, 0);
    #pragma unroll
    for (int mi = 0; mi < 8; ++mi)
      acc[mi][1] = __builtin_amdgcn_mfma_f32_16x16x32_bf16(af[mi], b1, acc[mi][1], 0, 0, 0);
    __builtin_amdgcn_s_setprio(0);
    __builtin_amdgcn_s_barrier();

    // ---------- P4: no ds_reads, MFMA ni 2-3 ----------
    if (pf) STG(Bs + nb + 8192, Bt, boff, kn + 32);
    __builtin_amdgcn_s_barrier();
    __builtin_amdgcn_s_setprio(1);
    #pragma unroll
    for (int mi = 0; mi < 8; ++mi)
      acc[mi][2] = __builtin_amdgcn_mfma_f32_16x16x32_bf16(af[mi], b2, acc[mi][2], 0, 0, 0);
    #pragma unroll
    for (int mi = 0; mi < 8; ++mi)
      acc[mi][3] = __builtin_amdgcn_mfma_f32_16x16x32_bf16(af[mi], b3, acc[mi][3], 0, 0, 0);
    __builtin_amdgcn_s_setprio(0);
    asm volatile("s_waitcnt vmcnt(4)" ::: "memory");  // k0 halves of tile t+1
    __builtin_amdgcn_s_barrier();
    __builtin_amdgcn_sched_barrier(0);
  }
  #undef STG

  // epilogue
  #pragma unroll
  for (int mi = 0; mi < 8; ++mi) {
    const int row = m0 + wm*128 + mi*16 + quad*4;
    #pragma unroll
    for (int ni = 0; ni < 4; ++ni) {
      const int col = n0 + wn*64 + ni*16 + m16;
      #pragma unroll
      for (int r = 0; r < 4; ++r)
        O[(size_t)(row + r) * CDIM + col] = acc[mi][ni][r];
    }
  }
}

// stage-2 LoRA with fused epilogues (fin_k folded into z1):
//  z0: w = -softplus(-(w0 + hw@w2)) - 0.5        -> slot1
//  z1: a = sigmoid(a0 + ha@a2) -> slot4 ; then (fused fin_k, wave owns a full
//      64-col head): kk = normalize(kraw*k_k) -> slot6 ;
//      k = kraw*(1+(a-1)*k_a) -> slot2 in-place
//  z2: v = vraw + (v_first - vraw)*sigmoid(v0 + hv@v2)   (in-place slot3)
//  z3: g = hg@g2                                 -> slot5
__global__ __launch_bounds__(256) void gemm_s2(
    const short* __restrict__ hw, const short* __restrict__ ha,
    const short* __restrict__ hv, const short* __restrict__ hg,
    const short* __restrict__ w2t, const short* __restrict__ a2t,
    const short* __restrict__ v2t, const short* __restrict__ g2t,
    const float* __restrict__ w0, const float* __restrict__ a0,
    const float* __restrict__ v0, const float* __restrict__ vfirst,
    const float* __restrict__ kkc, const float* __restrict__ kac,
    float* __restrict__ out)
{
  __shared__ short As[4096], Bs[4096];
  const int z = blockIdx.z;
  const short* A  = (z==0) ? hw  : (z==1) ? ha  : (z==2) ? hv  : hg;
  const short* Bt = (z==0) ? w2t : (z==1) ? a2t : (z==2) ? v2t : g2t;
  const int K = (z==2) ? 64 : (z==3) ? 224 : 128;
  const int m0 = blockIdx.x * 128, n0 = blockIdx.y * 128;
  f32x4 acc[4][4];
  gemm_core(threadIdx.x, A, K, Bt, K, K, m0, n0, As, Bs, acc);

  const int tid=threadIdx.x, lane=tid&63, wv=tid>>6;
  const int wy=wv>>1, wx=wv&1, quad=lane>>4, m16=lane&15;
  #pragma unroll
  for (int mi = 0; mi < 4; ++mi) {
    const int mb = m0 + wy*64 + mi*16 + quad*4;
    if (z == 1) {
      // a + fused fin_k: this wave's 4 ni-fragments cover exactly one
      // 64-col head (n0 + wx*64 .. +64); rows fixed per (quad,r).
      #pragma unroll
      for (int r = 0; r < 4; ++r) {
        float av[4], kr[4], kkv[4];
        float ss = 0.f;
        #pragma unroll
        for (int ni = 0; ni < 4; ++ni) {
          const int n = n0 + wx*64 + ni*16 + m16;
          const size_t idx = (size_t)(mb + r) * CDIM + n;
          av[ni] = sigm(a0[n] + acc[mi][ni][r]);
          kr[ni] = out[2*SLOT + idx];
          kkv[ni] = kr[ni] * kkc[n];
          ss += kkv[ni] * kkv[ni];
        }
        ss += __shfl_xor(ss, 1, 64);
        ss += __shfl_xor(ss, 2, 64);
        ss += __shfl_xor(ss, 4, 64);
        ss += __shfl_xor(ss, 8, 64);
        const float inv = 1.f / fmaxf(sqrtf(ss), 1e-12f);
        #pragma unroll
        for (int ni = 0; ni < 4; ++ni) {
          const int n = n0 + wx*64 + ni*16 + m16;
          const size_t idx = (size_t)(mb + r) * CDIM + n;
          out[4*SLOT + idx] = av[ni];
          out[2*SLOT + idx] = kr[ni] * (1.f + (av[ni] - 1.f) * kac[n]);
          out[6*SLOT + idx] = kkv[ni] * inv;
        }
      }
    } else {
      #pragma unroll
      for (int ni = 0; ni < 4; ++ni) {
        const int n = n0 + wx*64 + ni*16 + m16;
        #pragma unroll
        for (int r = 0; r < 4; ++r) {
          const float val = acc[mi][ni][r];
          const size_t idx = (size_t)(mb + r) * CDIM + n;
          if (z == 0) {
            float zz = w0[n] + val;
            float sp = fmaxf(-zz, 0.f) + log1pf(expf(-fabsf(zz)));
            out[SLOT + idx] = -sp - 0.5f;
          } else if (z == 2) {
            const float gate = sigm(v0[n] + val);
            const float vr = out[3*SLOT + idx];
            out[3*SLOT + idx] = vr + (vfirst[idx] - vr) * gate;
          } else {
            out[5*SLOT + idx] = val;
          }
        }
      }
    }
  }
}

extern "C" void kernel_launch(void* const* d_in, const int* in_sizes, int n_in,
                              void* d_out, int out_size, void* d_ws, size_t ws_size,
                              hipStream_t stream) {
  (void)in_sizes; (void)n_in; (void)out_size; (void)ws_size;
  const float* x   = (const float*)d_in[0];
  const float* vf  = (const float*)d_in[1];
  const float* x_r = (const float*)d_in[2];
  const float* x_w = (const float*)d_in[3];
  const float* x_k = (const float*)d_in[4];
  const float* x_v = (const float*)d_in[5];
  const float* x_a = (const float*)d_in[6];
  const float* x_g = (const float*)d_in[7];
  const float* w0  = (const float*)d_in[8];
  const float* w1  = (const float*)d_in[9];
  const float* w2  = (const float*)d_in[10];
  const float* a0  = (const float*)d_in[11];
  const float* a1  = (const float*)d_in[12];
  const float* a2  = (const float*)d_in[13];
  const float* v0  = (const float*)d_in[14];
  const float* v1  = (const float*)d_in[15];
  const float* v2  = (const float*)d_in[16];
  const float* g1  = (const float*)d_in[17];
  const float* g2  = (const float*)d_in[18];
  const float* k_k = (const float*)d_in[19];
  const float* k_a = (const float*)d_in[20];
  const float* Wr  = (const float*)d_in[21];
  const float* Wk  = (const float*)d_in[22];
  const float* Wv  = (const float*)d_in[23];

  float* out = (float*)d_out;

  // bf16 mixed activations live in not-yet-final output slots (w,a,g + k,v):
  // dead before those slots are written by gemm_s2 (stream-ordered after the
  // combined gemm_big2 dispatch which is their only consumer).
  short* xr_b = (short*)(out + 1*SLOT);
  short* xw_b = xr_b + SLOT;
  short* xk_b = (short*)(out + 4*SLOT);
  short* xv_b = xk_b + SLOT;
  short* xa_b = (short*)(out + 5*SLOT);
  short* xg_b = xa_b + SLOT;

  // workspace: bf16 weights + LoRA hiddens (~40 MB)
  char* wsp = (char*)d_ws;
  size_t off = 0;
  #define ALLOC(var, bytes) short* var = (short*)(wsp + off); off += (((size_t)(bytes)) + 255) & ~(size_t)255;
  ALLOC(Wr_b, (size_t)CDIM*CDIM*2)
  ALLOC(Wk_b, (size_t)CDIM*CDIM*2)
  ALLOC(Wv_b, (size_t)CDIM*CDIM*2)
  ALLOC(w1t, 128*2048*2)
  ALLOC(a1t, 128*2048*2)
  ALLOC(v1t, 128*2048*2)   // zero-padded rows 64..127
  ALLOC(g1t, 256*2048*2)   // zero-padded rows 224..255
  ALLOC(w2t, 2048*128*2)
  ALLOC(a2t, 2048*128*2)
  ALLOC(v2t, 2048*64*2)
  ALLOC(g2t, 2048*224*2)
  ALLOC(hw, (size_t)MTOT*128*2)
  ALLOC(ha, (size_t)MTOT*128*2)
  ALLOC(hv, (size_t)MTOT*64*2)
  ALLOC(hg, (size_t)MTOT*224*2)
  #undef ALLOC

  front<<<dim3(45056), 256, 0, stream>>>(
      x, vf, x_r, x_w, x_k, x_v, x_a, x_g,
      Wr, Wk, Wv, w1, a1, v1, g1, w2, a2, v2, g2,
      xr_b, xw_b, xk_b, xv_b, xa_b, xg_b, out + 7*SLOT,
      Wr_b, Wk_b, Wv_b, w1t, a1t, v1t, g1t, w2t, a2t, v2t, g2t);

  gemm_big2<<<dim3(32, 8, 4), 512, 0, stream>>>(
      xr_b, xk_b, xv_b, Wr_b, Wk_b, Wv_b,
      xw_b, xa_b, xg_b, w1t, a1t, v1t, g1t,
      hw, ha, hv, hg, out);

  gemm_s2<<<dim3(64, 16, 4), 256, 0, stream>>>(
      hw, ha, hv, hg, w2t, a2t, v2t, g2t, w0, a0, v0, vf, k_k, k_a, out);
}

// Round 5
// 1228.241 us; speedup vs baseline: 1.1476x; 1.0141x over previous
//
#include <hip/hip_runtime.h>
#include <hip/hip_bf16.h>

#define MTOT 8192              // B*T
#define TLEN 4096              // T
#define CDIM 2048              // C
#define SLOT ((size_t)MTOT * CDIM)   // elements per output tensor

typedef __attribute__((ext_vector_type(4))) float f32x4;
typedef __attribute__((ext_vector_type(8))) __bf16 bf16x8;

__device__ __forceinline__ short f2bf(float f) {
  __hip_bfloat16 h = __float2bfloat16(f);
  return __builtin_bit_cast(short, h);
}

__device__ __forceinline__ float sigm(float x) { return 1.f / (1.f + expf(-x)); }

__device__ __forceinline__ void stnt(float* p, float v) {
  __builtin_nontemporal_store(v, p);
}

// async global->LDS, 16B per lane; LDS dest = wave-uniform base + lane*16
__device__ __forceinline__ void gload16(const void* g, void* l) {
  __builtin_amdgcn_global_load_lds(
      (__attribute__((address_space(1))) void*)g,
      (__attribute__((address_space(3))) void*)l, 16, 0, 0);
}

// ---------------------------------------------------------------------------
// Core 128x128 tile GEMM (NT): C[m,n] = sum_k A[m,k] * Bt[n,k]
// 256 threads (4 waves), BK=32, 16x16x32 bf16 MFMA, 4x4 acc per wave.
// T3-minimum pipeline: LDS double-buffer (As/Bs = 2 x 4096 elems each,
// 16KB regions), counted vmcnt(4) -- prefetch of tile t+2 stays in flight
// across the raw s_barrier (no __syncthreads vmcnt(0) drain).
// tid is the LOCAL 0..255 thread id (callers may be 512-thread blocks split
// into two independent halves -- both halves run identical trip counts so
// the barriers stay block-aligned).
// ---------------------------------------------------------------------------
__device__ __forceinline__ void gemm_core(
    int tid,
    const short* __restrict__ A, int lda,
    const short* __restrict__ Bt, int ldb,
    int K, int m0, int n0,
    short* As, short* Bs, f32x4 acc[4][4])
{
  const int lane = tid & 63;
  const int wv   = tid >> 6;        // wave 0..3 (within half)
  const int wy   = wv >> 1;
  const int wx   = wv & 1;
  const int quad = lane >> 4;
  const int m16  = lane & 15;

  const f32x4 zero = {0.f, 0.f, 0.f, 0.f};
  #pragma unroll
  for (int i = 0; i < 4; ++i)
    #pragma unroll
    for (int j = 0; j < 4; ++j)
      acc[i][j] = zero;

  const int e0 = (wv * 64 + lane) * 8;   // element offset of chunk 0
  const int e1 = e0 + 2048;              // chunk 1
  const int r0 = e0 >> 5, c0 = e0 & 31;
  const int r1 = e1 >> 5, c1 = e1 & 31;
  const int lb0 = wv * 512;              // LDS base (elems), wave-uniform
  const int lb1 = 2048 + wv * 512;

  const short* pa0 = A  + (size_t)(m0 + r0) * lda + c0;
  const short* pa1 = A  + (size_t)(m0 + r1) * lda + c1;
  const short* pb0 = Bt + (size_t)(n0 + r0) * ldb + c0;
  const short* pb1 = Bt + (size_t)(n0 + r1) * ldb + c1;

  const int NTk = K >> 5;

  #define STG1(T, BUF) do { const int kk_ = (T) * 32; \
    gload16(pa0 + kk_, As + (BUF)*4096 + lb0); \
    gload16(pa1 + kk_, As + (BUF)*4096 + lb1); \
    gload16(pb0 + kk_, Bs + (BUF)*4096 + lb0); \
    gload16(pb1 + kk_, Bs + (BUF)*4096 + lb1); } while (0)

  STG1(0, 0);
  if (NTk > 1) STG1(1, 1);

  for (int t = 0; t < NTk; ++t) {
    const int buf = (t & 1) * 4096;
    // wait for tile t's 4 loads (FIFO); keep tile t+1's 4 in flight
    if (t + 1 < NTk) asm volatile("s_waitcnt vmcnt(4)" ::: "memory");
    else             asm volatile("s_waitcnt vmcnt(0)" ::: "memory");
    __builtin_amdgcn_s_barrier();
    __builtin_amdgcn_sched_barrier(0);

    bf16x8 af[4], bfr[4];
    #pragma unroll
    for (int mi = 0; mi < 4; ++mi)
      af[mi] = *(const bf16x8*)(As + buf + (wy*64 + mi*16 + m16)*32 + quad*8);
    #pragma unroll
    for (int ni = 0; ni < 4; ++ni)
      bfr[ni] = *(const bf16x8*)(Bs + buf + (wx*64 + ni*16 + m16)*32 + quad*8);

    #pragma unroll
    for (int mi = 0; mi < 4; ++mi)
      #pragma unroll
      for (int ni = 0; ni < 4; ++ni)
        acc[mi][ni] = __builtin_amdgcn_mfma_f32_16x16x32_bf16(
            af[mi], bfr[ni], acc[mi][ni], 0, 0, 0);

    __builtin_amdgcn_s_barrier();      // all waves done reading buf
    __builtin_amdgcn_sched_barrier(0);
    if (t + 2 < NTk) STG1(t + 2, buf == 0 ? 0 : 1);
  }
  #undef STG1
}

// ---------------------------------------------------------------------------
// front: merged {mix, cvt_big, wtrans} -- independent prep work, one launch.
//  blocks [0,16384)          : mix (xx-coef blends -> bf16)
//  blocks [16384,28672)      : Wr/Wk/Wv fp32->bf16
//  blocks [28672,45056)      : small-weight transpose/pad -> bf16 [N,K]
// (v_first copy moved into gemm_s2 z2, which reads vfirst anyway)
// ---------------------------------------------------------------------------
__global__ __launch_bounds__(256) void front(
    const float* __restrict__ x,
    const float* __restrict__ cr, const float* __restrict__ cw,
    const float* __restrict__ ck, const float* __restrict__ cv,
    const float* __restrict__ ca, const float* __restrict__ cg,
    const float* __restrict__ Wr, const float* __restrict__ Wk,
    const float* __restrict__ Wv,
    const float* __restrict__ w1, const float* __restrict__ a1,
    const float* __restrict__ v1, const float* __restrict__ g1,
    const float* __restrict__ w2, const float* __restrict__ a2,
    const float* __restrict__ v2, const float* __restrict__ g2,
    short* __restrict__ xr, short* __restrict__ xw, short* __restrict__ xk,
    short* __restrict__ xv, short* __restrict__ xa, short* __restrict__ xg,
    short* __restrict__ Wrb, short* __restrict__ Wkb, short* __restrict__ Wvb,
    short* __restrict__ w1t, short* __restrict__ a1t,
    short* __restrict__ v1t, short* __restrict__ g1t,
    short* __restrict__ w2t, short* __restrict__ a2t,
    short* __restrict__ v2t, short* __restrict__ g2t)
{
  const int b = blockIdx.x;
  const int tidx = threadIdx.x;

  if (b < 16384) {
    // ---- mix ----
    const size_t i = (size_t)b * 256 + tidx;     // over MTOT*CDIM/4
    const size_t e = i * 4;
    const int c = (int)(e & (CDIM - 1));
    const size_t m = e >> 11;                    // / CDIM
    const int t = (int)(m & (TLEN - 1));
    const float4 xc = *(const float4*)(x + e);
    float4 xp = make_float4(0.f, 0.f, 0.f, 0.f);
    if (t > 0) xp = *(const float4*)(x + e - CDIM);
    const float d0 = xp.x - xc.x, d1 = xp.y - xc.y;
    const float d2 = xp.z - xc.z, d3 = xp.w - xc.w;

    #define EMIT(coef, dst) { \
      const float4 cf = *(const float4*)((coef) + c); \
      short4 s; \
      s.x = f2bf(xc.x + d0 * cf.x); \
      s.y = f2bf(xc.y + d1 * cf.y); \
      s.z = f2bf(xc.z + d2 * cf.z); \
      s.w = f2bf(xc.w + d3 * cf.w); \
      *(short4*)((dst) + e) = s; }
    EMIT(cr, xr) EMIT(cw, xw) EMIT(ck, xk) EMIT(cv, xv) EMIT(ca, xa) EMIT(cg, xg)
    #undef EMIT
  } else if (b < 28672) {
    // ---- cvt_big ----
    const int lb = b - 16384;
    const int z = lb >> 12;                      // 0..2
    const int xb = lb & 4095;
    const float* src = (z == 0) ? Wr : (z == 1) ? Wk : Wv;
    short* dst = (z == 0) ? Wrb : (z == 1) ? Wkb : Wvb;
    const size_t e = ((size_t)xb * 256 + tidx) * 4;   // over CDIM*CDIM
    const float4 v = *(const float4*)(src + e);
    short4 s;
    s.x = f2bf(v.x); s.y = f2bf(v.y); s.z = f2bf(v.z); s.w = f2bf(v.w);
    *(short4*)(dst + e) = s;
  } else {
    // ---- wtrans ----
    const int lb = b - 28672;
    const int task = lb >> 11;                   // 0..7
    const int i = (lb & 2047) * 256 + tidx;
    switch (task) {
      case 0: if (i < 128*2048) { int d=i>>11, c=i&2047; w1t[i]=f2bf(w1[(size_t)c*128+d]); } break;
      case 1: if (i < 128*2048) { int d=i>>11, c=i&2047; a1t[i]=f2bf(a1[(size_t)c*128+d]); } break;
      case 2: if (i < 128*2048) { int d=i>>11, c=i&2047; v1t[i]=(d<64)?f2bf(v1[(size_t)c*64+d]):(short)0; } break;
      case 3: if (i < 256*2048) { int d=i>>11, c=i&2047; g1t[i]=(d<224)?f2bf(g1[(size_t)c*224+d]):(short)0; } break;
      case 4: if (i < 2048*128) { int c=i>>7, d=i&127; w2t[i]=f2bf(w2[(size_t)d*2048+c]); } break;
      case 5: if (i < 2048*128) { int c=i>>7, d=i&127; a2t[i]=f2bf(a2[(size_t)d*2048+c]); } break;
      case 6: if (i < 2048*64)  { int c=i>>6, d=i&63;  v2t[i]=f2bf(v2[(size_t)d*2048+c]); } break;
      case 7: if (i < 2048*224) { int c=i/224, d=i-c*224; g2t[i]=f2bf(g2[(size_t)d*2048+c]); } break;
    }
  }
}

// ---------------------------------------------------------------------------
// big projections, 256x256 tile, BK=64, 8 waves, 4-phase/K-tile counted-vmcnt
// pipeline (T2 swizzle + T3/T4 counted vmcnt + T5 setprio).
//   z0: r = xr@Wr^T -> slot0 (nt store, never re-read)
//   z1: kraw = xk@Wk^T -> slot2 (cached store, re-read by s2)
//   z2: vraw = xv@Wv^T -> slot3 (cached store, re-read by s2)
//   z3: stage-1 LoRA tiles (two independent 128^2 gemm_core halves per block)
// XCD-aware decomposition: flat&7 selects the n-panel == dispatch-XCD, so
// each XCD keeps ONE 1MB B-panel L2-resident while A streams via L3.
// ---------------------------------------------------------------------------
__global__ __launch_bounds__(512, 2) void gemm_big2(
    const short* __restrict__ xr, const short* __restrict__ xk,
    const short* __restrict__ xv,
    const short* __restrict__ Wr, const short* __restrict__ Wk,
    const short* __restrict__ Wv,
    const short* __restrict__ xw, const short* __restrict__ xa,
    const short* __restrict__ xg,
    const short* __restrict__ w1t, const short* __restrict__ a1t,
    const short* __restrict__ v1t, const short* __restrict__ g1t,
    short* __restrict__ hw, short* __restrict__ ha,
    short* __restrict__ hv, short* __restrict__ hg,
    float* __restrict__ out)
{
  __shared__ short As[32768];   // 64KB: [db:16384][ks:8192] elems
  __shared__ short Bs[32768];   // 64KB

  const int z = blockIdx.z;

  if (z == 3) {
    // ------- stage-1 LoRA path: 160 blocks, 2 independent halves each -------
    const int flat = blockIdx.x + (blockIdx.y << 5);
    if (flat >= 160) return;
    const int sub = threadIdx.x >> 8;            // half 0/1
    const int tid = threadIdx.x & 255;
    const int tile = flat * 2 + sub;             // 0..319
    const int t = tile >> 6;                     // 0..4 task
    const int mt = tile & 63;
    const short* A1 = (t==0) ? xw  : (t==1) ? xa  : (t==2) ? xv  : xg;
    const short* B1 = (t==0) ? w1t : (t==1) ? a1t : (t==2) ? v1t : g1t;
    short* H        = (t==0) ? hw  : (t==1) ? ha  : (t==2) ? hv  : hg;
    const int Nreal = (t==2) ? 64 : (t>=3) ? 224 : 128;
    const int n0 = (t==4) ? 128 : 0;
    const int m0 = mt * 128;
    short* sA = As + sub * 8192;                 // 16KB dbuf region per half
    short* sB = Bs + sub * 8192;
    f32x4 acc[4][4];
    gemm_core(tid, A1, CDIM, B1, CDIM, CDIM, m0, n0, sA, sB, acc);

    const int lane=tid&63, wv=tid>>6;
    const int wy=wv>>1, wx=wv&1, quad=lane>>4, m16=lane&15;
    #pragma unroll
    for (int mi = 0; mi < 4; ++mi) {
      const int mb = m0 + wy*64 + mi*16 + quad*4;
      #pragma unroll
      for (int ni = 0; ni < 4; ++ni) {
        const int n = n0 + wx*64 + ni*16 + m16;
        if (n < Nreal) {
          #pragma unroll
          for (int r = 0; r < 4; ++r) {
            float v = acc[mi][ni][r];
            if (t == 0) v = tanhf(v);
            else if (t >= 3) v = sigm(v);
            H[(size_t)(mb + r) * Nreal + n] = f2bf(v);
          }
        }
      }
    }
    return;
  }

  // ---------------- main 256x256 pipelined path ----------------
  const short* A  = (z == 0) ? xr : (z == 1) ? xk : xv;
  const short* Bt = (z == 0) ? Wr : (z == 1) ? Wk : Wv;
  float* O = (z == 0) ? out : (z == 1) ? out + 2*SLOT : out + 3*SLOT;

  const int flat = blockIdx.x + (blockIdx.y << 5);   // 0..255
  const int m0 = (flat >> 3) * 256;                  // 32 m-tiles
  const int n0 = (flat & 7)  * 256;                  // 8 n-tiles == 8 XCDs
  const int tid  = threadIdx.x;          // 0..511
  const int lane = tid & 63, wid = tid >> 6;
  const int wm = wid >> 2, wn = wid & 3; // 2 x 4 wave grid
  const int quad = lane >> 4, m16 = lane & 15;

  // ---- staging geometry (per thread, constant over K) ----
  const int srow = tid >> 2;                                 // 0..127
  const int csrc = (((tid & 3) ^ ((tid >> 3) & 3)) << 3);    // pre-swizzled col chunk
  const size_t aoff = (size_t)(m0 + srow) * CDIM + csrc;
  const size_t boff = (size_t)(n0 + srow) * CDIM + csrc;
  const int lbase = wid * 512;           // wave-uniform lane0 elem offset

  // ---- fragment read offsets (swizzled) ----
  const int fslot = ((quad ^ ((m16 >> 1) & 3)) << 3);        // elem offset in row
  const int abase = (wm*128 + m16) * 32 + fslot;
  const int bbase = (wn*64  + m16) * 32 + fslot;

  f32x4 acc[8][4];
  const f32x4 zf = {0.f, 0.f, 0.f, 0.f};
  #pragma unroll
  for (int i = 0; i < 8; ++i)
    #pragma unroll
    for (int j = 0; j < 4; ++j) acc[i][j] = zf;

  // stage one 256x32 half (2 x global_load_lds per thread)
  #define STG(REG, BASEP, OFF, KOFF) do { \
    gload16((BASEP) + (OFF) + (KOFF), (REG) + lbase); \
    gload16((BASEP) + (OFF) + (KOFF) + (size_t)128*CDIM, (REG) + lbase + 4096); \
  } while (0)

  // prologue: tile 0 into dbuf 0, order A_k0, B_k0, A_k1, B_k1
  STG(As + 0,    A,  aoff, 0);
  STG(Bs + 0,    Bt, boff, 0);
  STG(As + 8192, A,  aoff, 32);
  STG(Bs + 8192, Bt, boff, 32);
  asm volatile("s_waitcnt vmcnt(4)" ::: "memory");   // k0 halves resident
  __builtin_amdgcn_s_barrier();
  __builtin_amdgcn_sched_barrier(0);

  const int NT = CDIM / 64;
  for (int t = 0; t < NT; ++t) {
    const int db = (t & 1) << 14;        // 0 / 16384
    const int nb = 16384 - db;
    const int kn = t*64 + 64;
    const bool pf = (kn < CDIM);
    short* Ar0 = As + db;                // tile t, ks=0
    short* Br0 = Bs + db;
    short* Ar1 = As + db + 8192;         // tile t, ks=1
    short* Br1 = Bs + db + 8192;

    bf16x8 af[8], b0, b1, b2, b3;

    // ---------- P1: ks0 reads (12x ds_read_b128), MFMA ni 0-1 ----------
    #pragma unroll
    for (int mi = 0; mi < 8; ++mi)
      af[mi] = *(const bf16x8*)(Ar0 + abase + mi*512);
    b0 = *(const bf16x8*)(Br0 + bbase + 0*512);
    b1 = *(const bf16x8*)(Br0 + bbase + 1*512);
    b2 = *(const bf16x8*)(Br0 + bbase + 2*512);
    b3 = *(const bf16x8*)(Br0 + bbase + 3*512);
    if (pf) STG(As + nb, A, aoff, kn);
    __builtin_amdgcn_s_barrier();
    asm volatile("s_waitcnt lgkmcnt(0)" ::: "memory");
    __builtin_amdgcn_sched_barrier(0);
    __builtin_amdgcn_s_setprio(1);
    #pragma unroll
    for (int mi = 0; mi < 8; ++mi)
      acc[mi][0] = __builtin_amdgcn_mfma_f32_16x16x32_bf16(af[mi], b0, acc[mi][0], 0, 0, 0);
    #pragma unroll
    for (int mi = 0; mi < 8; ++mi)
      acc[mi][1] = __builtin_amdgcn_mfma_f32_16x16x32_bf16(af[mi], b1, acc[mi][1], 0, 0, 0);
    __builtin_amdgcn_s_setprio(0);
    __builtin_amdgcn_s_barrier();

    // ---------- P2: no ds_reads, MFMA ni 2-3 ----------
    if (pf) STG(Bs + nb, Bt, boff, kn);
    __builtin_amdgcn_s_barrier();
    __builtin_amdgcn_s_setprio(1);
    #pragma unroll
    for (int mi = 0; mi < 8; ++mi)
      acc[mi][2] = __builtin_amdgcn_mfma_f32_16x16x32_bf16(af[mi], b2, acc[mi][2], 0, 0, 0);
    #pragma unroll
    for (int mi = 0; mi < 8; ++mi)
      acc[mi][3] = __builtin_amdgcn_mfma_f32_16x16x32_bf16(af[mi], b3, acc[mi][3], 0, 0, 0);
    __builtin_amdgcn_s_setprio(0);
    if (pf) asm volatile("s_waitcnt vmcnt(4)" ::: "memory");  // k1 halves of tile t
    else    asm volatile("s_waitcnt vmcnt(0)" ::: "memory");
    __builtin_amdgcn_s_barrier();
    __builtin_amdgcn_sched_barrier(0);

    // ---------- P3: ks1 reads (12x), MFMA ni 0-1 ----------
    #pragma unroll
    for (int mi = 0; mi < 8; ++mi)
      af[mi] = *(const bf16x8*)(Ar1 + abase + mi*512);
    b0 = *(const bf16x8*)(Br1 + bbase + 0*512);
    b1 = *(const bf16x8*)(Br1 + bbase + 1*512);
    b2 = *(const bf16x8*)(Br1 + bbase + 2*512);
    b3 = *(const bf16x8*)(Br1 + bbase + 3*512);
    if (pf) STG(As + nb + 8192, A, aoff, kn + 32);
    __builtin_amdgcn_s_barrier();
    asm volatile("s_waitcnt lgkmcnt(0)" ::: "memory");
    __builtin_amdgcn_sched_barrier(0);
    __builtin_amdgcn_s_setprio(1);
    #pragma unroll
    for (int mi = 0; mi < 8; ++mi)
      acc[mi][0] = __builtin_amdgcn_mfma_f32_16x16x32_bf16(af[mi], b0, acc[mi][0], 0, 0, 0);
    #pragma unroll
    for (int mi = 0; mi < 8; ++mi)
      acc[mi][1] = __builtin_amdgcn_mfma_f32_16x16x32_bf16(af[mi], b1, acc[mi][1], 0, 0, 0);
    __builtin_amdgcn_s_setprio(0);
    __builtin_amdgcn_s_barrier();

    // ---------- P4: no ds_reads, MFMA ni 2-3 ----------
    if (pf) STG(Bs + nb + 8192, Bt, boff, kn + 32);
    __builtin_amdgcn_s_barrier();
    __builtin_amdgcn_s_setprio(1);
    #pragma unroll
    for (int mi = 0; mi < 8; ++mi)
      acc[mi][2] = __builtin_amdgcn_mfma_f32_16x16x32_bf16(af[mi], b2, acc[mi][2], 0, 0, 0);
    #pragma unroll
    for (int mi = 0; mi < 8; ++mi)
      acc[mi][3] = __builtin_amdgcn_mfma_f32_16x16x32_bf16(af[mi], b3, acc[mi][3], 0, 0, 0);
    __builtin_amdgcn_s_setprio(0);
    asm volatile("s_waitcnt vmcnt(4)" ::: "memory");  // k0 halves of tile t+1
    __builtin_amdgcn_s_barrier();
    __builtin_amdgcn_sched_barrier(0);
  }
  #undef STG

  // epilogue: z0 (r) is final -> nt store; z1/z2 re-read by s2 -> cached
  #pragma unroll
  for (int mi = 0; mi < 8; ++mi) {
    const int row = m0 + wm*128 + mi*16 + quad*4;
    #pragma unroll
    for (int ni = 0; ni < 4; ++ni) {
      const int col = n0 + wn*64 + ni*16 + m16;
      #pragma unroll
      for (int r = 0; r < 4; ++r) {
        float* p = O + (size_t)(row + r) * CDIM + col;
        if (z == 0) stnt(p, acc[mi][ni][r]);
        else        *p = acc[mi][ni][r];
      }
    }
  }
}

// stage-2 LoRA with fused epilogues (fin_k folded into z1, vf copy into z2):
//  z0: w = -softplus(-(w0 + hw@w2)) - 0.5        -> slot1
//  z1: a = sigmoid(a0 + ha@a2) -> slot4 ; kk = normalize(kraw*k_k) -> slot6 ;
//      k = kraw*(1+(a-1)*k_a) -> slot2 in-place
//  z2: v = vraw + (v_first - vraw)*sigmoid(v0 + hv@v2) -> slot3 in-place ;
//      vfout = v_first -> slot7
//  z3: g = hg@g2                                 -> slot5
// All outputs final -> nt stores.
__global__ __launch_bounds__(256) void gemm_s2(
    const short* __restrict__ hw, const short* __restrict__ ha,
    const short* __restrict__ hv, const short* __restrict__ hg,
    const short* __restrict__ w2t, const short* __restrict__ a2t,
    const short* __restrict__ v2t, const short* __restrict__ g2t,
    const float* __restrict__ w0, const float* __restrict__ a0,
    const float* __restrict__ v0, const float* __restrict__ vfirst,
    const float* __restrict__ kkc, const float* __restrict__ kac,
    float* __restrict__ out)
{
  __shared__ short As[8192], Bs[8192];   // 16KB + 16KB dbuf regions
  const int z = blockIdx.z;
  const short* A  = (z==0) ? hw  : (z==1) ? ha  : (z==2) ? hv  : hg;
  const short* Bt = (z==0) ? w2t : (z==1) ? a2t : (z==2) ? v2t : g2t;
  const int K = (z==2) ? 64 : (z==3) ? 224 : 128;
  const int m0 = blockIdx.x * 128, n0 = blockIdx.y * 128;
  f32x4 acc[4][4];
  gemm_core(threadIdx.x, A, K, Bt, K, K, m0, n0, As, Bs, acc);

  const int tid=threadIdx.x, lane=tid&63, wv=tid>>6;
  const int wy=wv>>1, wx=wv&1, quad=lane>>4, m16=lane&15;
  #pragma unroll
  for (int mi = 0; mi < 4; ++mi) {
    const int mb = m0 + wy*64 + mi*16 + quad*4;
    if (z == 1) {
      // a + fused fin_k: this wave's 4 ni-fragments cover exactly one
      // 64-col head (n0 + wx*64 .. +64); rows fixed per (quad,r).
      #pragma unroll
      for (int r = 0; r < 4; ++r) {
        float av[4], kr[4], kkv[4];
        float ss = 0.f;
        #pragma unroll
        for (int ni = 0; ni < 4; ++ni) {
          const int n = n0 + wx*64 + ni*16 + m16;
          const size_t idx = (size_t)(mb + r) * CDIM + n;
          av[ni] = sigm(a0[n] + acc[mi][ni][r]);
          kr[ni] = out[2*SLOT + idx];
          kkv[ni] = kr[ni] * kkc[n];
          ss += kkv[ni] * kkv[ni];
        }
        ss += __shfl_xor(ss, 1, 64);
        ss += __shfl_xor(ss, 2, 64);
        ss += __shfl_xor(ss, 4, 64);
        ss += __shfl_xor(ss, 8, 64);
        const float inv = 1.f / fmaxf(sqrtf(ss), 1e-12f);
        #pragma unroll
        for (int ni = 0; ni < 4; ++ni) {
          const int n = n0 + wx*64 + ni*16 + m16;
          const size_t idx = (size_t)(mb + r) * CDIM + n;
          stnt(out + 4*SLOT + idx, av[ni]);
          stnt(out + 2*SLOT + idx, kr[ni] * (1.f + (av[ni] - 1.f) * kac[n]));
          stnt(out + 6*SLOT + idx, kkv[ni] * inv);
        }
      }
    } else {
      #pragma unroll
      for (int ni = 0; ni < 4; ++ni) {
        const int n = n0 + wx*64 + ni*16 + m16;
        #pragma unroll
        for (int r = 0; r < 4; ++r) {
          const float val = acc[mi][ni][r];
          const size_t idx = (size_t)(mb + r) * CDIM + n;
          if (z == 0) {
            float zz = w0[n] + val;
            float sp = fmaxf(-zz, 0.f) + log1pf(expf(-fabsf(zz)));
            stnt(out + SLOT + idx, -sp - 0.5f);
          } else if (z == 2) {
            const float vfv = vfirst[idx];
            const float gate = sigm(v0[n] + val);
            const float vr = out[3*SLOT + idx];
            stnt(out + 3*SLOT + idx, vr + (vfv - vr) * gate);
            stnt(out + 7*SLOT + idx, vfv);
          } else {
            stnt(out + 5*SLOT + idx, val);
          }
        }
      }
    }
  }
}

extern "C" void kernel_launch(void* const* d_in, const int* in_sizes, int n_in,
                              void* d_out, int out_size, void* d_ws, size_t ws_size,
                              hipStream_t stream) {
  (void)in_sizes; (void)n_in; (void)out_size; (void)ws_size;
  const float* x   = (const float*)d_in[0];
  const float* vf  = (const float*)d_in[1];
  const float* x_r = (const float*)d_in[2];
  const float* x_w = (const float*)d_in[3];
  const float* x_k = (const float*)d_in[4];
  const float* x_v = (const float*)d_in[5];
  const float* x_a = (const float*)d_in[6];
  const float* x_g = (const float*)d_in[7];
  const float* w0  = (const float*)d_in[8];
  const float* w1  = (const float*)d_in[9];
  const float* w2  = (const float*)d_in[10];
  const float* a0  = (const float*)d_in[11];
  const float* a1  = (const float*)d_in[12];
  const float* a2  = (const float*)d_in[13];
  const float* v0  = (const float*)d_in[14];
  const float* v1  = (const float*)d_in[15];
  const float* v2  = (const float*)d_in[16];
  const float* g1  = (const float*)d_in[17];
  const float* g2  = (const float*)d_in[18];
  const float* k_k = (const float*)d_in[19];
  const float* k_a = (const float*)d_in[20];
  const float* Wr  = (const float*)d_in[21];
  const float* Wk  = (const float*)d_in[22];
  const float* Wv  = (const float*)d_in[23];

  float* out = (float*)d_out;

  // bf16 mixed activations live in not-yet-final output slots:
  // xr,xw in slots 1..2 ; xk,xv,xa,xg in slots 4..6. All are dead before
  // those slots are written by gemm_s2 (stream-ordered after gemm_big2,
  // their only consumer).
  short* xr_b = (short*)(out + 1*SLOT);
  short* xw_b = xr_b + SLOT;
  short* xk_b = (short*)(out + 4*SLOT);
  short* xv_b = xk_b + SLOT;
  short* xa_b = (short*)(out + 5*SLOT);
  short* xg_b = xa_b + SLOT;

  // workspace: bf16 weights + LoRA hiddens (~40 MB)
  char* wsp = (char*)d_ws;
  size_t off = 0;
  #define ALLOC(var, bytes) short* var = (short*)(wsp + off); off += (((size_t)(bytes)) + 255) & ~(size_t)255;
  ALLOC(Wr_b, (size_t)CDIM*CDIM*2)
  ALLOC(Wk_b, (size_t)CDIM*CDIM*2)
  ALLOC(Wv_b, (size_t)CDIM*CDIM*2)
  ALLOC(w1t, 128*2048*2)
  ALLOC(a1t, 128*2048*2)
  ALLOC(v1t, 128*2048*2)   // zero-padded rows 64..127
  ALLOC(g1t, 256*2048*2)   // zero-padded rows 224..255
  ALLOC(w2t, 2048*128*2)
  ALLOC(a2t, 2048*128*2)
  ALLOC(v2t, 2048*64*2)
  ALLOC(g2t, 2048*224*2)
  ALLOC(hw, (size_t)MTOT*128*2)
  ALLOC(ha, (size_t)MTOT*128*2)
  ALLOC(hv, (size_t)MTOT*64*2)
  ALLOC(hg, (size_t)MTOT*224*2)
  #undef ALLOC

  front<<<dim3(45056), 256, 0, stream>>>(
      x, x_r, x_w, x_k, x_v, x_a, x_g,
      Wr, Wk, Wv, w1, a1, v1, g1, w2, a2, v2, g2,
      xr_b, xw_b, xk_b, xv_b, xa_b, xg_b,
      Wr_b, Wk_b, Wv_b, w1t, a1t, v1t, g1t, w2t, a2t, v2t, g2t);

  gemm_big2<<<dim3(32, 8, 4), 512, 0, stream>>>(
      xr_b, xk_b, xv_b, Wr_b, Wk_b, Wv_b,
      xw_b, xa_b, xg_b, w1t, a1t, v1t, g1t,
      hw, ha, hv, hg, out);

  gemm_s2<<<dim3(64, 16, 4), 256, 0, stream>>>(
      hw, ha, hv, hg, w2t, a2t, v2t, g2t, w0, a0, v0, vf, k_k, k_a, out);
}